// Round 5
// baseline (1206.418 us; speedup 1.0000x reference)
//
#include <hip/hip_runtime.h>

// B=4, S=2048, E=2048, H=16, D=128, ROT_DIM=128 (full-head rope).
// Inputs/outputs are FLOAT32 (per the reference; the bf16 in the harness
// label refers to the comparison path). Internal compute: bf16 MFMA with f32
// accumulate; the 8.25e-2 threshold permits bf16 rounding (~0.02).
// Memory plan: Q (bf16, 32 MiB) -> d_out lower half; K,V (bf16) -> ws[0,64MiB).
// attn writes ctx (bf16) in place over Q; GEMM2 reads ctx, writes f32 out to
// ws[0,64MiB) (K/V dead), then D2D copy ws -> d_out (64 MiB).

using frag_ab = __attribute__((ext_vector_type(8))) short;   // 8 bf16 = 4 VGPRs
using frag_cd = __attribute__((ext_vector_type(4))) float;   // 4 f32 acc

__device__ __forceinline__ float b2f(unsigned short u) {
  union { unsigned int i; float f; } v; v.i = ((unsigned int)u) << 16; return v.f;
}
__device__ __forceinline__ unsigned short f2b(float f) {
  union { float f; unsigned int i; } v; v.f = f;
  unsigned int r = v.i + 0x7FFFu + ((v.i >> 16) & 1u);   // RNE
  return (unsigned short)(r >> 16);
}
__device__ __forceinline__ unsigned int pack2(float a, float b) {
  return (unsigned int)f2b(a) | ((unsigned int)f2b(b) << 16);
}

constexpr int BK = 64, LDK = BK + 8;   // LDS row stride (2-way aliasing free, m136)

// ---------------------------------------------------------------------------
// GEMM1: qkv = x @ wqkv_w^T + bias (f32 in), scattered as bf16 to Q/K/V in
// (B,H,S,D). col c: h=c/384, slot=(c%384)>>7, d=c&127.
// 128x128 tile, BK=64, 4 waves 2x2, 16x16x32 bf16 MFMA; f32->bf16 at staging.
// ---------------------------------------------------------------------------
__global__ __launch_bounds__(256)
void gemm_qkv(const float* __restrict__ A,    // x (8192,2048) f32
              const float* __restrict__ B,    // wqkv_w (6144,2048) f32
              const float* __restrict__ bias, // (6144,) f32
              unsigned short* __restrict__ Qb,
              unsigned short* __restrict__ Kb,
              unsigned short* __restrict__ Vb) {
  __shared__ __align__(16) unsigned short As[128 * LDK];
  __shared__ __align__(16) unsigned short Bs[128 * LDK];
  const int tid  = threadIdx.x;
  const int wave = tid >> 6, lane = tid & 63;
  const int quad = lane >> 4, l16 = lane & 15;
  const int wm = (wave & 1) * 64, wn = (wave >> 1) * 64;
  const int row0A = blockIdx.x * 128;
  const int row0B = blockIdx.y * 128;

  frag_cd acc[4][4];
#pragma unroll
  for (int i = 0; i < 4; i++)
#pragma unroll
    for (int j = 0; j < 4; j++) acc[i][j] = (frag_cd){0.f, 0.f, 0.f, 0.f};

  for (int k0 = 0; k0 < 2048; k0 += BK) {
    // stage 128x64 f32 tiles -> bf16 LDS: 2048 float4-chunks each, 8/thread
#pragma unroll
    for (int i = 0; i < 8; i++) {
      int c = tid + i * 256;
      int r = c >> 4, col4 = (c & 15) * 4;
      float4 av = *(const float4*)&A[(long)(row0A + r) * 2048 + k0 + col4];
      float4 bv = *(const float4*)&B[(long)(row0B + r) * 2048 + k0 + col4];
      uint2 ap, bp;
      ap.x = pack2(av.x, av.y); ap.y = pack2(av.z, av.w);
      bp.x = pack2(bv.x, bv.y); bp.y = pack2(bv.z, bv.w);
      *(uint2*)&As[r * LDK + col4] = ap;
      *(uint2*)&Bs[r * LDK + col4] = bp;
    }
    __syncthreads();
#pragma unroll
    for (int kk = 0; kk < BK; kk += 32) {
      frag_ab af[4], bf[4];
#pragma unroll
      for (int mi = 0; mi < 4; mi++)
        af[mi] = *(const frag_ab*)&As[(wm + mi * 16 + l16) * LDK + kk + quad * 8];
#pragma unroll
      for (int ni = 0; ni < 4; ni++)
        bf[ni] = *(const frag_ab*)&Bs[(wn + ni * 16 + l16) * LDK + kk + quad * 8];
#pragma unroll
      for (int mi = 0; mi < 4; mi++)
#pragma unroll
        for (int ni = 0; ni < 4; ni++)
          acc[mi][ni] = __builtin_amdgcn_mfma_f32_16x16x32_bf16(af[mi], bf[ni], acc[mi][ni], 0, 0, 0);
    }
    __syncthreads();
  }
  // C/D layout: col=lane&15, row=quad*4+reg (m89). Scatter bf16 to Q/K/V.
#pragma unroll
  for (int ni = 0; ni < 4; ni++) {
    int col  = row0B + wn + ni * 16 + l16;
    int h    = col / 384;            // wave-uniform per ni (16-group never straddles 384)
    int rem  = col - h * 384;
    int slot = rem >> 7;
    int d    = rem & 127;
    unsigned short* dst = (slot == 0) ? Qb : ((slot == 1) ? Kb : Vb);
    float bv = bias[col];
#pragma unroll
    for (int mi = 0; mi < 4; mi++) {
#pragma unroll
      for (int r = 0; r < 4; r++) {
        int row = row0A + wm + mi * 16 + quad * 4 + r;
        int b = row >> 11, s = row & 2047;
        dst[((long)(b * 16 + h) * 2048 + s) * 128 + d] = f2b(acc[mi][ni][r] + bv);
      }
    }
  }
}

// ---------------------------------------------------------------------------
// In-place deinterleave + RoPE on bf16 Q and K, (B,H,S,D).
// One wave per (bh, s, part); lane j reads pair (2j,2j+1), writes j, 64+j.
// ---------------------------------------------------------------------------
__global__ __launch_bounds__(256)
void rope_inplace(unsigned short* __restrict__ Qb, unsigned short* __restrict__ Kb) {
  int wid  = blockIdx.x * 4 + (threadIdx.x >> 6);   // [0, 262144)
  int j    = threadIdx.x & 63;
  int part = wid & 1;
  int s    = (wid >> 1) & 2047;
  int bh   = wid >> 12;                              // [0, 64)
  unsigned short* buf = part ? Kb : Qb;
  long base = ((long)bh * 2048 + s) * 128;
  unsigned int pr = *(const unsigned int*)&buf[base + 2 * j];
  float x1 = b2f((unsigned short)(pr & 0xFFFFu));
  float x2 = b2f((unsigned short)(pr >> 16));
  float inv = powf(10000.0f, -(float)(2 * j) / 128.0f);
  float ang = (float)s * inv;
  float sn, cs;
  sincosf(ang, &sn, &cs);
  buf[base + j]      = f2b(x1 * cs - x2 * sn);
  buf[base + 64 + j] = f2b(x1 * sn + x2 * cs);
}

// ---------------------------------------------------------------------------
// Causal flash attention, bf16 (B,H,S,D) buffers. ctx written IN PLACE over Q
// (block (bh,qt) is the only reader of its Q rows, register-resident at start).
// ---------------------------------------------------------------------------
constexpr int LDH = 136;  // 128 + 8 pad

__global__ __launch_bounds__(256)
void attn_fwd(unsigned short* __restrict__ Qc,        // Q in, ctx out (in place)
              const unsigned short* __restrict__ K,
              const unsigned short* __restrict__ V) {
  __shared__ __align__(16) unsigned short Ks[32 * LDH];
  __shared__ __align__(16) unsigned short Vs[32 * LDH];
  __shared__ __align__(16) unsigned short Ps[4][32 * 40];
  const int bh = blockIdx.x;          // b*16 + h
  const int qt = blockIdx.y;
  const int tid = threadIdx.x;
  const int wave = tid >> 6, lane = tid & 63;
  const int quad = lane >> 4, l16 = lane & 15;
  const long base = (long)bh * 2048 * 128;
  const int q0 = qt * 128 + wave * 32;
  const float scale = 0.08838834764831845f;  // 1/sqrt(128)

  frag_ab qf[2][4];
#pragma unroll
  for (int mi = 0; mi < 2; mi++)
#pragma unroll
    for (int ks = 0; ks < 4; ks++)
      qf[mi][ks] = *(const frag_ab*)&Qc[base + (long)(q0 + mi * 16 + l16) * 128 + ks * 32 + quad * 8];

  frag_cd o[2][8];
#pragma unroll
  for (int mi = 0; mi < 2; mi++)
#pragma unroll
    for (int ni = 0; ni < 8; ni++) o[mi][ni] = (frag_cd){0.f, 0.f, 0.f, 0.f};
  float m_i[2][4], l_i[2][4];
#pragma unroll
  for (int mi = 0; mi < 2; mi++)
#pragma unroll
    for (int r = 0; r < 4; r++) { m_i[mi][r] = -1.0e30f; l_i[mi][r] = 0.f; }

  const int kv_end = qt * 128 + 128;
  for (int kv0 = 0; kv0 < kv_end; kv0 += 32) {
    __syncthreads();   // prev iter's readers of Ks/Vs done
#pragma unroll
    for (int i = 0; i < 2; i++) {
      int c = tid + i * 256;
      int r = c >> 4, col = (c & 15) * 8;
      long rowb = base + (long)(kv0 + r) * 128 + col;
      *(uint4*)&Ks[r * LDH + col] = *(const uint4*)&K[rowb];
      *(uint4*)&Vs[r * LDH + col] = *(const uint4*)&V[rowb];
    }
    __syncthreads();

    // S = Q @ K^T (32x32 per wave), scale + causal mask
    float p[2][2][4];
#pragma unroll
    for (int ni = 0; ni < 2; ni++) {
      frag_ab kf[4];
#pragma unroll
      for (int ks = 0; ks < 4; ks++)
        kf[ks] = *(const frag_ab*)&Ks[(ni * 16 + l16) * LDH + ks * 32 + quad * 8];
#pragma unroll
      for (int mi = 0; mi < 2; mi++) {
        frag_cd acc = (frag_cd){0.f, 0.f, 0.f, 0.f};
#pragma unroll
        for (int ks = 0; ks < 4; ks++)
          acc = __builtin_amdgcn_mfma_f32_16x16x32_bf16(qf[mi][ks], kf[ks], acc, 0, 0, 0);
        int colg = kv0 + ni * 16 + l16;
#pragma unroll
        for (int r = 0; r < 4; r++) {
          int rowg = q0 + mi * 16 + quad * 4 + r;
          float sc = acc[r] * scale;
          p[mi][ni][r] = (colg <= rowg) ? sc : -10000.0f;
        }
      }
    }

    // online softmax (row = mi*16 + quad*4 + r; cols across 16 lanes x 2 ni)
#pragma unroll
    for (int mi = 0; mi < 2; mi++) {
#pragma unroll
      for (int r = 0; r < 4; r++) {
        float mx = fmaxf(p[mi][0][r], p[mi][1][r]);
#pragma unroll
        for (int off = 1; off < 16; off <<= 1)
          mx = fmaxf(mx, __shfl_xor(mx, off, 64));
        float mnew  = fmaxf(m_i[mi][r], mx);
        float alpha = __expf(m_i[mi][r] - mnew);
        float e0 = __expf(p[mi][0][r] - mnew);
        float e1 = __expf(p[mi][1][r] - mnew);
        p[mi][0][r] = e0; p[mi][1][r] = e1;
        float rs = e0 + e1;
#pragma unroll
        for (int off = 1; off < 16; off <<= 1)
          rs += __shfl_xor(rs, off, 64);
        l_i[mi][r] = l_i[mi][r] * alpha + rs;
        m_i[mi][r] = mnew;
#pragma unroll
        for (int ni = 0; ni < 8; ni++) o[mi][ni][r] *= alpha;
      }
    }

    // P (C-layout) -> LDS -> A-layout (m120 pattern)
    unsigned short* pw = &Ps[wave][0];
#pragma unroll
    for (int mi = 0; mi < 2; mi++)
#pragma unroll
      for (int ni = 0; ni < 2; ni++)
#pragma unroll
        for (int r = 0; r < 4; r++)
          pw[(mi * 16 + quad * 4 + r) * 40 + ni * 16 + l16] = f2b(p[mi][ni][r]);
    __syncthreads();

    // O += P @ V
#pragma unroll
    for (int ni = 0; ni < 8; ni++) {
      frag_ab vf;
#pragma unroll
      for (int j = 0; j < 8; j++)
        vf[j] = (short)Vs[(quad * 8 + j) * LDH + ni * 16 + l16];
#pragma unroll
      for (int mi = 0; mi < 2; mi++) {
        frag_ab pf = *(const frag_ab*)&pw[(mi * 16 + l16) * 40 + quad * 8];
        o[mi][ni] = __builtin_amdgcn_mfma_f32_16x16x32_bf16(pf, vf, o[mi][ni], 0, 0, 0);
      }
    }
  }

  // in-place epilogue: Qc[bh, s, :] = O / l
#pragma unroll
  for (int mi = 0; mi < 2; mi++) {
#pragma unroll
    for (int r = 0; r < 4; r++) {
      float inv = 1.0f / fmaxf(l_i[mi][r], 1.0e-20f);
      int s = q0 + mi * 16 + quad * 4 + r;
      long rowb = base + (long)s * 128;
#pragma unroll
      for (int ni = 0; ni < 8; ni++) {
        float val = o[mi][ni][r] * inv;
        val = fminf(fmaxf(val, -3.0e38f), 3.0e38f);
        Qc[rowb + ni * 16 + l16] = f2b(val);
      }
    }
  }
}

// ---------------------------------------------------------------------------
// GEMM2: out(f32) = ctx(bf16,B,H,S,D) @ wo_w(f32)^T + wo_b(f32).
// ctx element (row=b*2048+s, k) at ((b*16+(k>>7))*2048+s)*128 + (k&127).
// ---------------------------------------------------------------------------
__global__ __launch_bounds__(256)
void gemm_ctx(const unsigned short* __restrict__ Actx,  // ctx bf16 (B,H,S,D)
              const float* __restrict__ B,              // wo_w (2048,2048) f32
              const float* __restrict__ bias,           // (2048,) f32
              float* __restrict__ C) {                  // (8192,2048) f32
  __shared__ __align__(16) unsigned short As[128 * LDK];
  __shared__ __align__(16) unsigned short Bs[128 * LDK];
  const int tid  = threadIdx.x;
  const int wave = tid >> 6, lane = tid & 63;
  const int quad = lane >> 4, l16 = lane & 15;
  const int wm = (wave & 1) * 64, wn = (wave >> 1) * 64;
  const int row0A = blockIdx.x * 128;
  const int row0B = blockIdx.y * 128;

  frag_cd acc[4][4];
#pragma unroll
  for (int i = 0; i < 4; i++)
#pragma unroll
    for (int j = 0; j < 4; j++) acc[i][j] = (frag_cd){0.f, 0.f, 0.f, 0.f};

  for (int k0 = 0; k0 < 2048; k0 += BK) {
    // A: bf16 gather from bhsd, 1024 uint4-chunks, 4/thread
#pragma unroll
    for (int i = 0; i < 4; i++) {
      int c = tid + i * 256;
      int r = c >> 3, colc = (c & 7) * 8;
      int row = row0A + r;
      int b = row >> 11, s = row & 2047;
      int kg = k0 + colc;
      int h = kg >> 7, d = kg & 127;
      *(uint4*)&As[r * LDK + colc] = *(const uint4*)&Actx[((long)(b * 16 + h) * 2048 + s) * 128 + d];
    }
    // B: f32 -> bf16, 2048 float4-chunks, 8/thread
#pragma unroll
    for (int i = 0; i < 8; i++) {
      int c = tid + i * 256;
      int r = c >> 4, col4 = (c & 15) * 4;
      float4 bv = *(const float4*)&B[(long)(row0B + r) * 2048 + k0 + col4];
      uint2 bp;
      bp.x = pack2(bv.x, bv.y); bp.y = pack2(bv.z, bv.w);
      *(uint2*)&Bs[r * LDK + col4] = bp;
    }
    __syncthreads();
#pragma unroll
    for (int kk = 0; kk < BK; kk += 32) {
      frag_ab af[4], bf[4];
#pragma unroll
      for (int mi = 0; mi < 4; mi++)
        af[mi] = *(const frag_ab*)&As[(wm + mi * 16 + l16) * LDK + kk + quad * 8];
#pragma unroll
      for (int ni = 0; ni < 4; ni++)
        bf[ni] = *(const frag_ab*)&Bs[(wn + ni * 16 + l16) * LDK + kk + quad * 8];
#pragma unroll
      for (int mi = 0; mi < 4; mi++)
#pragma unroll
        for (int ni = 0; ni < 4; ni++)
          acc[mi][ni] = __builtin_amdgcn_mfma_f32_16x16x32_bf16(af[mi], bf[ni], acc[mi][ni], 0, 0, 0);
    }
    __syncthreads();
  }
#pragma unroll
  for (int ni = 0; ni < 4; ni++) {
    int col = row0B + wn + ni * 16 + l16;
    float bv = bias[col];
#pragma unroll
    for (int mi = 0; mi < 4; mi++) {
#pragma unroll
      for (int r = 0; r < 4; r++) {
        int row = row0A + wm + mi * 16 + quad * 4 + r;
        C[(long)row * 2048 + col] = acc[mi][ni][r] + bv;
      }
    }
  }
}

// ---------------------------------------------------------------------------
extern "C" void kernel_launch(void* const* d_in, const int* in_sizes, int n_in,
                              void* d_out, int out_size, void* d_ws, size_t ws_size,
                              hipStream_t stream) {
  const float* x      = (const float*)d_in[0];  // (4,2048,2048) f32
  const float* wqkv_w = (const float*)d_in[1];  // (6144,2048) f32
  const float* wqkv_b = (const float*)d_in[2];  // (6144,) f32
  const float* wo_w   = (const float*)d_in[3];  // (2048,2048) f32
  const float* wo_b   = (const float*)d_in[4];  // (2048,) f32
  float* out = (float*)d_out;                   // (4,2048,2048) f32 = 64 MiB

  unsigned short* Qb = (unsigned short*)d_out;                     // lower 32 MiB of d_out
  unsigned short* Kb = (unsigned short*)d_ws;                      // 32 MiB
  unsigned short* Vb = (unsigned short*)((char*)d_ws + 33554432L); // 32 MiB
  float* out2 = (float*)d_ws;                                      // 64 MiB (K/V dead by then)

  // 1) QKV projection (f32 in, bf16 out), scattered to (B,H,S,D)
  gemm_qkv<<<dim3(64, 48), 256, 0, stream>>>(x, wqkv_w, wqkv_b, Qb, Kb, Vb);
  // 2) deinterleave + rope in place on Q and K
  rope_inplace<<<65536, 256, 0, stream>>>(Qb, Kb);
  // 3) causal flash attention; ctx (bf16) overwrites Q in place
  attn_fwd<<<dim3(64, 16), 256, 0, stream>>>(Qb, Kb, Vb);
  // 4) out = ctx @ wo_w^T + wo_b (f32) -> ws, then copy into d_out
  gemm_ctx<<<dim3(64, 16), 256, 0, stream>>>(Qb, wo_w, wo_b, out2);
  hipMemcpyAsync(out, out2, 67108864UL, hipMemcpyDeviceToDevice, stream);
}

// Round 6
// 1079.606 us; speedup vs baseline: 1.1175x; 1.1175x over previous
//
#include <hip/hip_runtime.h>

// B=4, S=2048, E=2048, H=16, D=128, full-head rope. f32 I/O, bf16 MFMA inside.
// Memory plan (ws <= 64 MiB, proven safe):
//   prep: xb = bf16(x) -> d_out[0,32MiB)
//   GEMM1 (A=xb via global_load_lds, B=wqkv_w inline cvt):
//     Q -> d_out[32,64MiB) (B,H,S,D); K -> ws[0,32) (B,H,S,D); V^T -> ws[32,64) (B,H,D,S)
//   rope in place on Q,K
//   attn: ctx (bf16, row-major B,S,E) -> d_out[0,32MiB) (xb dead)
//   GEMM2 (A=ctx via global_load_lds, B=wo_w inline cvt) -> f32 ws[0,64MiB)
//   D2D copy ws -> d_out.

using frag_ab = __attribute__((ext_vector_type(8))) short;   // 8 bf16 = 4 VGPRs
using frag_cd = __attribute__((ext_vector_type(4))) float;   // 4 f32 acc

__device__ __forceinline__ float b2f(unsigned short u) {
  union { unsigned int i; float f; } v; v.i = ((unsigned int)u) << 16; return v.f;
}
__device__ __forceinline__ unsigned short f2b(float f) {
  union { float f; unsigned int i; } v; v.f = f;
  unsigned int r = v.i + 0x7FFFu + ((v.i >> 16) & 1u);   // RNE
  return (unsigned short)(r >> 16);
}
__device__ __forceinline__ unsigned int pack2(float a, float b) {
  return (unsigned int)f2b(a) | ((unsigned int)f2b(b) << 16);
}
// async global->LDS, 16B per lane; LDS dest = wave-uniform base + lane*16
__device__ __forceinline__ void gload16(const unsigned short* g, unsigned short* l) {
  __builtin_amdgcn_global_load_lds(
      (const __attribute__((address_space(1))) unsigned int*)g,
      (__attribute__((address_space(3))) unsigned int*)l, 16, 0, 0);
}

constexpr int LDK = 72;   // padded LDS stride for cvt-staged B tiles

// ---------------------------------------------------------------------------
// f32 -> bf16 bulk convert (8 elems/thread)
// ---------------------------------------------------------------------------
__global__ __launch_bounds__(256)
void cvt_f32_bf16(const float* __restrict__ in, unsigned short* __restrict__ out) {
  long i = (long)(blockIdx.x * 256 + threadIdx.x) * 8;
  float4 a = *(const float4*)&in[i];
  float4 b = *(const float4*)&in[i + 4];
  uint4 p;
  p.x = pack2(a.x, a.y); p.y = pack2(a.z, a.w);
  p.z = pack2(b.x, b.y); p.w = pack2(b.z, b.w);
  *(uint4*)&out[i] = p;
}

// ---------------------------------------------------------------------------
// GEMM1: qkv = xb(bf16) @ wqkv_w(f32->bf16)^T + bias, scattered to
// Q (B,H,S,D), K (B,H,S,D), V^T (B,H,D,S). A staged via global_load_lds.
// ---------------------------------------------------------------------------
__global__ __launch_bounds__(256)
void gemm_qkv(const unsigned short* __restrict__ A,  // xb (8192,2048) bf16
              const float* __restrict__ Bw,          // wqkv_w (6144,2048) f32
              const float* __restrict__ bias,        // (6144,)
              unsigned short* __restrict__ Qb,
              unsigned short* __restrict__ Kb,
              unsigned short* __restrict__ Vt) {
  __shared__ __align__(16) unsigned short As[128 * 64];   // unpadded (async dest)
  __shared__ __align__(16) unsigned short Bs[128 * LDK];
  const int tid  = threadIdx.x;
  const int wave = tid >> 6, lane = tid & 63;
  const int quad = lane >> 4, l16 = lane & 15;
  const int wm = (wave & 1) * 64, wn = (wave >> 1) * 64;
  const int row0A = blockIdx.x * 128;
  const int row0B = blockIdx.y * 128;

  frag_cd acc[4][4];
#pragma unroll
  for (int i = 0; i < 4; i++)
#pragma unroll
    for (int j = 0; j < 4; j++) acc[i][j] = (frag_cd){0.f, 0.f, 0.f, 0.f};

  for (int k0 = 0; k0 < 2048; k0 += 64) {
    // A: 16 KB tile, 16 async 1KB stages (4 per wave)
#pragma unroll
    for (int i = 0; i < 4; i++) {
      int rbase = wave * 32 + i * 8;
      gload16(&A[(long)(row0A + rbase + (lane >> 3)) * 2048 + k0 + (lane & 7) * 8],
              &As[rbase * 64]);
    }
    // B: f32 -> bf16 inline, padded stride
#pragma unroll
    for (int i = 0; i < 8; i++) {
      int c = tid + i * 256;
      int r = c >> 4, col4 = (c & 15) * 4;
      float4 bv = *(const float4*)&Bw[(long)(row0B + r) * 2048 + k0 + col4];
      uint2 bp; bp.x = pack2(bv.x, bv.y); bp.y = pack2(bv.z, bv.w);
      *(uint2*)&Bs[r * LDK + col4] = bp;
    }
    __syncthreads();
#pragma unroll
    for (int kk = 0; kk < 64; kk += 32) {
      frag_ab af[4], bf[4];
#pragma unroll
      for (int mi = 0; mi < 4; mi++)
        af[mi] = *(const frag_ab*)&As[(wm + mi * 16 + l16) * 64 + kk + quad * 8];
#pragma unroll
      for (int ni = 0; ni < 4; ni++)
        bf[ni] = *(const frag_ab*)&Bs[(wn + ni * 16 + l16) * LDK + kk + quad * 8];
#pragma unroll
      for (int mi = 0; mi < 4; mi++)
#pragma unroll
        for (int ni = 0; ni < 4; ni++)
          acc[mi][ni] = __builtin_amdgcn_mfma_f32_16x16x32_bf16(af[mi], bf[ni], acc[mi][ni], 0, 0, 0);
    }
    __syncthreads();
  }
  // scatter epilogue. col c: h=c/384, slot=(c%384)>>7, d=c&127 (wave-uniform per ni)
#pragma unroll
  for (int ni = 0; ni < 4; ni++) {
    int col  = row0B + wn + ni * 16 + l16;
    int h    = col / 384;
    int rem  = col - h * 384;
    int slot = rem >> 7;
    int d    = rem & 127;
    float bv = bias[col];
#pragma unroll
    for (int mi = 0; mi < 4; mi++) {
#pragma unroll
      for (int r = 0; r < 4; r++) {
        int row = row0A + wm + mi * 16 + quad * 4 + r;
        int b = row >> 11, s = row & 2047;
        unsigned short val = f2b(acc[mi][ni][r] + bv);
        if (slot == 0)      Qb[((long)(b * 16 + h) * 2048 + s) * 128 + d] = val;
        else if (slot == 1) Kb[((long)(b * 16 + h) * 2048 + s) * 128 + d] = val;
        else                Vt[((long)(b * 16 + h) * 128 + d) * 2048 + s] = val;
      }
    }
  }
}

// ---------------------------------------------------------------------------
// In-place deinterleave + RoPE on bf16 Q and K, (B,H,S,D).
// ---------------------------------------------------------------------------
__global__ __launch_bounds__(256)
void rope_inplace(unsigned short* __restrict__ Qb, unsigned short* __restrict__ Kb) {
  int wid  = blockIdx.x * 4 + (threadIdx.x >> 6);   // [0, 262144)
  int j    = threadIdx.x & 63;
  int part = wid & 1;
  int s    = (wid >> 1) & 2047;
  int bh   = wid >> 12;                              // [0, 64)
  unsigned short* buf = part ? Kb : Qb;
  long base = ((long)bh * 2048 + s) * 128;
  unsigned int pr = *(const unsigned int*)&buf[base + 2 * j];
  float x1 = b2f((unsigned short)(pr & 0xFFFFu));
  float x2 = b2f((unsigned short)(pr >> 16));
  float inv = powf(10000.0f, -(float)(2 * j) / 128.0f);
  float ang = (float)s * inv;
  float sn, cs;
  sincosf(ang, &sn, &cs);
  buf[base + j]      = f2b(x1 * cs - x2 * sn);
  buf[base + 64 + j] = f2b(x1 * sn + x2 * cs);
}

// ---------------------------------------------------------------------------
// Causal flash attention. Q,K (B,H,S,D); V^T (B,H,D,S). ctx -> row-major
// (B,S,E) bf16. K staged via global_load_lds (tile contiguous in bhsd);
// V^T staged manually into padded LDS -> V-fragments are single b128 reads.
// ---------------------------------------------------------------------------
constexpr int LDV = 40;  // Vt LDS row stride (32+8); 80B rows, 16B-aligned

__global__ __launch_bounds__(256)
void attn_fwd(const unsigned short* __restrict__ Q,
              const unsigned short* __restrict__ K,
              const unsigned short* __restrict__ Vt,
              unsigned short* __restrict__ ctx) {
  __shared__ __align__(16) unsigned short Ks[32 * 128];     // unpadded (async dest)
  __shared__ __align__(16) unsigned short Vs[128 * LDV];    // transposed [d][kv]
  __shared__ __align__(16) unsigned short Ps[4][32 * 40];
  const int bh = blockIdx.x;          // b*16 + h
  const int qt = blockIdx.y;
  const int tid = threadIdx.x;
  const int wave = tid >> 6, lane = tid & 63;
  const int quad = lane >> 4, l16 = lane & 15;
  const long base  = (long)bh * 2048 * 128;   // Q/K rows
  const int q0 = qt * 128 + wave * 32;
  const float scale = 0.08838834764831845f;  // 1/sqrt(128)

  frag_ab qf[2][4];
#pragma unroll
  for (int mi = 0; mi < 2; mi++)
#pragma unroll
    for (int ks = 0; ks < 4; ks++)
      qf[mi][ks] = *(const frag_ab*)&Q[base + (long)(q0 + mi * 16 + l16) * 128 + ks * 32 + quad * 8];

  frag_cd o[2][8];
#pragma unroll
  for (int mi = 0; mi < 2; mi++)
#pragma unroll
    for (int ni = 0; ni < 8; ni++) o[mi][ni] = (frag_cd){0.f, 0.f, 0.f, 0.f};
  float m_i[2][4], l_i[2][4];
#pragma unroll
  for (int mi = 0; mi < 2; mi++)
#pragma unroll
    for (int r = 0; r < 4; r++) { m_i[mi][r] = -1.0e30f; l_i[mi][r] = 0.f; }

  const int kv_end = qt * 128 + 128;
  for (int kv0 = 0; kv0 < kv_end; kv0 += 32) {
    __syncthreads();   // prev iter's readers done
    // K tile: 8 KB contiguous -> 8 async 1KB stages (2 per wave)
#pragma unroll
    for (int i = 0; i < 2; i++) {
      int cb = (wave * 2 + i) * 512;           // elem offset within tile
      gload16(&K[base + (long)kv0 * 128 + cb + lane * 8], &Ks[cb]);
    }
    // V^T tile: 128 x 32, manual staging into padded rows (2 chunks/thread)
#pragma unroll
    for (int i = 0; i < 2; i++) {
      int c = tid + i * 256;
      int d = c >> 2, colc = (c & 3) * 8;
      *(uint4*)&Vs[d * LDV + colc] =
          *(const uint4*)&Vt[(long)bh * 262144 + (long)d * 2048 + kv0 + colc];
    }
    __syncthreads();

    // S = Q @ K^T (32x32 per wave), scale + causal mask
    float p[2][2][4];
#pragma unroll
    for (int ni = 0; ni < 2; ni++) {
      frag_ab kf[4];
#pragma unroll
      for (int ks = 0; ks < 4; ks++)
        kf[ks] = *(const frag_ab*)&Ks[(ni * 16 + l16) * 128 + ks * 32 + quad * 8];
#pragma unroll
      for (int mi = 0; mi < 2; mi++) {
        frag_cd acc = (frag_cd){0.f, 0.f, 0.f, 0.f};
#pragma unroll
        for (int ks = 0; ks < 4; ks++)
          acc = __builtin_amdgcn_mfma_f32_16x16x32_bf16(qf[mi][ks], kf[ks], acc, 0, 0, 0);
        int colg = kv0 + ni * 16 + l16;
#pragma unroll
        for (int r = 0; r < 4; r++) {
          int rowg = q0 + mi * 16 + quad * 4 + r;
          float sc = acc[r] * scale;
          p[mi][ni][r] = (colg <= rowg) ? sc : -10000.0f;
        }
      }
    }

    // online softmax
#pragma unroll
    for (int mi = 0; mi < 2; mi++) {
#pragma unroll
      for (int r = 0; r < 4; r++) {
        float mx = fmaxf(p[mi][0][r], p[mi][1][r]);
#pragma unroll
        for (int off = 1; off < 16; off <<= 1)
          mx = fmaxf(mx, __shfl_xor(mx, off, 64));
        float mnew  = fmaxf(m_i[mi][r], mx);
        float alpha = __expf(m_i[mi][r] - mnew);
        float e0 = __expf(p[mi][0][r] - mnew);
        float e1 = __expf(p[mi][1][r] - mnew);
        p[mi][0][r] = e0; p[mi][1][r] = e1;
        float rs = e0 + e1;
#pragma unroll
        for (int off = 1; off < 16; off <<= 1)
          rs += __shfl_xor(rs, off, 64);
        l_i[mi][r] = l_i[mi][r] * alpha + rs;
        m_i[mi][r] = mnew;
#pragma unroll
        for (int ni = 0; ni < 8; ni++) o[mi][ni][r] *= alpha;
      }
    }

    // P (C-layout) -> LDS -> A-layout
    unsigned short* pw = &Ps[wave][0];
#pragma unroll
    for (int mi = 0; mi < 2; mi++)
#pragma unroll
      for (int ni = 0; ni < 2; ni++)
#pragma unroll
        for (int r = 0; r < 4; r++)
          pw[(mi * 16 + quad * 4 + r) * 40 + ni * 16 + l16] = f2b(p[mi][ni][r]);
    __syncthreads();

    // O += P @ V : V-fragment = single b128 from transposed tile
#pragma unroll
    for (int ni = 0; ni < 8; ni++) {
      frag_ab vf = *(const frag_ab*)&Vs[(ni * 16 + l16) * LDV + quad * 8];
#pragma unroll
      for (int mi = 0; mi < 2; mi++) {
        frag_ab pf = *(const frag_ab*)&pw[(mi * 16 + l16) * 40 + quad * 8];
        o[mi][ni] = __builtin_amdgcn_mfma_f32_16x16x32_bf16(pf, vf, o[mi][ni], 0, 0, 0);
      }
    }
  }

  // ctx row-major: ctx[(b*2048+s)*2048 + h*128 + d]
  const int b = bh >> 4, h = bh & 15;
#pragma unroll
  for (int mi = 0; mi < 2; mi++) {
#pragma unroll
    for (int r = 0; r < 4; r++) {
      float inv = 1.0f / fmaxf(l_i[mi][r], 1.0e-20f);
      int s = q0 + mi * 16 + quad * 4 + r;
      long rowb = ((long)b * 2048 + s) * 2048 + h * 128;
#pragma unroll
      for (int ni = 0; ni < 8; ni++)
        ctx[rowb + ni * 16 + l16] = f2b(o[mi][ni][r] * inv);
    }
  }
}

// ---------------------------------------------------------------------------
// GEMM2: out(f32) = ctx(bf16 row-major) @ wo_w(f32->bf16)^T + wo_b.
// A staged via global_load_lds.
// ---------------------------------------------------------------------------
__global__ __launch_bounds__(256)
void gemm_ctx(const unsigned short* __restrict__ A,   // ctx (8192,2048) bf16
              const float* __restrict__ Bw,           // wo_w (2048,2048) f32
              const float* __restrict__ bias,         // (2048,)
              float* __restrict__ C) {                // (8192,2048) f32
  __shared__ __align__(16) unsigned short As[128 * 64];
  __shared__ __align__(16) unsigned short Bs[128 * LDK];
  const int tid  = threadIdx.x;
  const int wave = tid >> 6, lane = tid & 63;
  const int quad = lane >> 4, l16 = lane & 15;
  const int wm = (wave & 1) * 64, wn = (wave >> 1) * 64;
  const int row0A = blockIdx.x * 128;
  const int row0B = blockIdx.y * 128;

  frag_cd acc[4][4];
#pragma unroll
  for (int i = 0; i < 4; i++)
#pragma unroll
    for (int j = 0; j < 4; j++) acc[i][j] = (frag_cd){0.f, 0.f, 0.f, 0.f};

  for (int k0 = 0; k0 < 2048; k0 += 64) {
#pragma unroll
    for (int i = 0; i < 4; i++) {
      int rbase = wave * 32 + i * 8;
      gload16(&A[(long)(row0A + rbase + (lane >> 3)) * 2048 + k0 + (lane & 7) * 8],
              &As[rbase * 64]);
    }
#pragma unroll
    for (int i = 0; i < 8; i++) {
      int c = tid + i * 256;
      int r = c >> 4, col4 = (c & 15) * 4;
      float4 bv = *(const float4*)&Bw[(long)(row0B + r) * 2048 + k0 + col4];
      uint2 bp; bp.x = pack2(bv.x, bv.y); bp.y = pack2(bv.z, bv.w);
      *(uint2*)&Bs[r * LDK + col4] = bp;
    }
    __syncthreads();
#pragma unroll
    for (int kk = 0; kk < 64; kk += 32) {
      frag_ab af[4], bf[4];
#pragma unroll
      for (int mi = 0; mi < 4; mi++)
        af[mi] = *(const frag_ab*)&As[(wm + mi * 16 + l16) * 64 + kk + quad * 8];
#pragma unroll
      for (int ni = 0; ni < 4; ni++)
        bf[ni] = *(const frag_ab*)&Bs[(wn + ni * 16 + l16) * LDK + kk + quad * 8];
#pragma unroll
      for (int mi = 0; mi < 4; mi++)
#pragma unroll
        for (int ni = 0; ni < 4; ni++)
          acc[mi][ni] = __builtin_amdgcn_mfma_f32_16x16x32_bf16(af[mi], bf[ni], acc[mi][ni], 0, 0, 0);
    }
    __syncthreads();
  }
#pragma unroll
  for (int ni = 0; ni < 4; ni++) {
    int col = row0B + wn + ni * 16 + l16;
    float bv = bias[col];
#pragma unroll
    for (int mi = 0; mi < 4; mi++) {
#pragma unroll
      for (int r = 0; r < 4; r++) {
        int row = row0A + wm + mi * 16 + quad * 4 + r;
        C[(long)row * 2048 + col] = acc[mi][ni][r] + bv;
      }
    }
  }
}

// ---------------------------------------------------------------------------
extern "C" void kernel_launch(void* const* d_in, const int* in_sizes, int n_in,
                              void* d_out, int out_size, void* d_ws, size_t ws_size,
                              hipStream_t stream) {
  const float* x      = (const float*)d_in[0];
  const float* wqkv_w = (const float*)d_in[1];
  const float* wqkv_b = (const float*)d_in[2];
  const float* wo_w   = (const float*)d_in[3];
  const float* wo_b   = (const float*)d_in[4];

  unsigned short* xb  = (unsigned short*)d_out;              // [0,32MiB) of d_out
  unsigned short* Qb  = (unsigned short*)d_out + 16777216;   // [32,64MiB)
  unsigned short* Kb  = (unsigned short*)d_ws;               // ws [0,32MiB)
  unsigned short* Vt  = (unsigned short*)d_ws + 16777216;    // ws [32,64MiB)
  unsigned short* ctx = (unsigned short*)d_out;              // over xb (dead)
  float* outf = (float*)d_ws;                                // ws [0,64MiB)

  // 0) x -> bf16
  cvt_f32_bf16<<<8192, 256, 0, stream>>>(x, xb);
  // 1) QKV projection: Q,K (bhsd) + V^T (bhds)
  gemm_qkv<<<dim3(64, 48), 256, 0, stream>>>(xb, wqkv_w, wqkv_b, Qb, Kb, Vt);
  // 2) rope in place on Q,K
  rope_inplace<<<65536, 256, 0, stream>>>(Qb, Kb);
  // 3) flash attention -> ctx row-major bf16
  attn_fwd<<<dim3(64, 16), 256, 0, stream>>>(Qb, Kb, Vt, ctx);
  // 4) output projection -> f32 in ws, then copy to d_out
  gemm_ctx<<<dim3(64, 16), 256, 0, stream>>>(ctx, wo_w, wo_b, outf);
  hipMemcpyAsync(d_out, outf, 67108864UL, hipMemcpyDeviceToDevice, stream);
}

// Round 7
// 834.026 us; speedup vs baseline: 1.4465x; 1.2945x over previous
//
#include <hip/hip_runtime.h>

// B=4, S=2048, E=2048, H=16, D=128, full-head rope. f32 I/O, bf16 MFMA inside.
// Memory plan:
//   d_out: xb [0,32MiB) -> later ctx (same region); Qb [32,64MiB)
//   ws:    Kb [0,32), Vt [32,64), optional Wq_bf [64,88), Wo_bf [88,96)
//   GEMM2 -> f32 ws[0,64MiB), D2D copy to d_out.
// LDS tiles staged by global_load_lds are XOR-swizzled (chunk ^= row&7) to
// break the 16-way bank conflicts of unpadded 128B-stride rows (r6 counters).

using frag_ab = __attribute__((ext_vector_type(8))) short;   // 8 bf16 = 4 VGPRs
using frag_cd = __attribute__((ext_vector_type(4))) float;   // 4 f32 acc

__device__ __forceinline__ float b2f(unsigned short u) {
  union { unsigned int i; float f; } v; v.i = ((unsigned int)u) << 16; return v.f;
}
__device__ __forceinline__ unsigned short f2b(float f) {
  union { float f; unsigned int i; } v; v.f = f;
  unsigned int r = v.i + 0x7FFFu + ((v.i >> 16) & 1u);   // RNE
  return (unsigned short)(r >> 16);
}
__device__ __forceinline__ unsigned int pack2(float a, float b) {
  return (unsigned int)f2b(a) | ((unsigned int)f2b(b) << 16);
}
__device__ __forceinline__ void gload16(const unsigned short* g, unsigned short* l) {
  __builtin_amdgcn_global_load_lds(
      (const __attribute__((address_space(1))) unsigned int*)g,
      (__attribute__((address_space(3))) unsigned int*)l, 16, 0, 0);
}

// ---------------------------------------------------------------------------
__global__ __launch_bounds__(256)
void cvt_f32_bf16(const float* __restrict__ in, unsigned short* __restrict__ out) {
  long i = (long)(blockIdx.x * 256 + threadIdx.x) * 8;
  float4 a = *(const float4*)&in[i];
  float4 b = *(const float4*)&in[i + 4];
  uint4 p;
  p.x = pack2(a.x, a.y); p.y = pack2(a.z, a.w);
  p.z = pack2(b.x, b.y); p.w = pack2(b.z, b.w);
  *(uint4*)&out[i] = p;
}

// ---------------------------------------------------------------------------
// Shared GEMM staging (128x64 bf16 tile, XOR-swizzled chunks).
// A always bf16 via global_load_lds. B: bf16 async if Bbf, else f32 inline cvt.
// Fragment read: phys chunk = (quad + kk/8) ^ (l16 & 7).
// ---------------------------------------------------------------------------
__device__ __forceinline__ void stage_a_async(const unsigned short* A, unsigned short* As,
                                              int row0, int k0, int wave, int lane, int ldk) {
#pragma unroll
  for (int i = 0; i < 4; i++) {
    int rbase = wave * 32 + i * 8;
    int r = rbase + (lane >> 3);
    int srcc = (lane & 7) ^ (r & 7);
    gload16(&A[(long)(row0 + r) * ldk + k0 + srcc * 8], &As[rbase * 64]);
  }
}
__device__ __forceinline__ void stage_b_cvt(const float* Bw, unsigned short* Bs,
                                            int row0, int k0, int tid) {
#pragma unroll
  for (int i = 0; i < 4; i++) {
    int c = tid + i * 256;                 // chunk id in [0,1024)
    int r = c >> 3, ch = c & 7;
    const float* src = &Bw[(long)(row0 + r) * 2048 + k0 + ch * 8];
    float4 v0 = *(const float4*)src;
    float4 v1 = *(const float4*)(src + 4);
    uint4 p;
    p.x = pack2(v0.x, v0.y); p.y = pack2(v0.z, v0.w);
    p.z = pack2(v1.x, v1.y); p.w = pack2(v1.z, v1.w);
    *(uint4*)&Bs[r * 64 + ((ch ^ (r & 7)) * 8)] = p;
  }
}

// ---------------------------------------------------------------------------
// GEMM1: qkv = xb @ W^T + bias -> Q (B,H,S,D), K (B,H,S,D), V^T (B,H,D,S)
// ---------------------------------------------------------------------------
__global__ __launch_bounds__(256)
void gemm_qkv(const unsigned short* __restrict__ A,    // xb (8192,2048) bf16
              const float* __restrict__ Bw,            // wqkv_w f32
              const unsigned short* __restrict__ Bbf,  // wqkv_w bf16 or null
              const float* __restrict__ bias,
              unsigned short* __restrict__ Qb,
              unsigned short* __restrict__ Kb,
              unsigned short* __restrict__ Vt) {
  __shared__ __align__(16) unsigned short As[128 * 64];
  __shared__ __align__(16) unsigned short Bs[128 * 64];
  const int tid  = threadIdx.x;
  const int wave = tid >> 6, lane = tid & 63;
  const int quad = lane >> 4, l16 = lane & 15;
  const int wm = (wave & 1) * 64, wn = (wave >> 1) * 64;
  const int row0A = blockIdx.x * 128;
  const int row0B = blockIdx.y * 128;

  frag_cd acc[4][4];
#pragma unroll
  for (int i = 0; i < 4; i++)
#pragma unroll
    for (int j = 0; j < 4; j++) acc[i][j] = (frag_cd){0.f, 0.f, 0.f, 0.f};

  for (int k0 = 0; k0 < 2048; k0 += 64) {
    stage_a_async(A, As, row0A, k0, wave, lane, 2048);
    if (Bbf) stage_a_async(Bbf, Bs, row0B, k0, wave, lane, 2048);
    else     stage_b_cvt(Bw, Bs, row0B, k0, tid);
    __syncthreads();
#pragma unroll
    for (int kk = 0; kk < 64; kk += 32) {
      frag_ab af[4], bf[4];
#pragma unroll
      for (int mi = 0; mi < 4; mi++) {
        int row = wm + mi * 16 + l16;
        af[mi] = *(const frag_ab*)&As[row * 64 + (((quad + (kk >> 3)) ^ (l16 & 7)) * 8)];
      }
#pragma unroll
      for (int ni = 0; ni < 4; ni++) {
        int row = wn + ni * 16 + l16;
        bf[ni] = *(const frag_ab*)&Bs[row * 64 + (((quad + (kk >> 3)) ^ (l16 & 7)) * 8)];
      }
#pragma unroll
      for (int mi = 0; mi < 4; mi++)
#pragma unroll
        for (int ni = 0; ni < 4; ni++)
          acc[mi][ni] = __builtin_amdgcn_mfma_f32_16x16x32_bf16(af[mi], bf[ni], acc[mi][ni], 0, 0, 0);
    }
    __syncthreads();
  }
  // scatter epilogue (C/D layout: col=l16, row=quad*4+r; m89-verified)
#pragma unroll
  for (int ni = 0; ni < 4; ni++) {
    int col  = row0B + wn + ni * 16 + l16;
    int h    = col / 384;
    int rem  = col - h * 384;
    int slot = rem >> 7;
    int d    = rem & 127;
    float bv = bias[col];
#pragma unroll
    for (int mi = 0; mi < 4; mi++) {
#pragma unroll
      for (int r = 0; r < 4; r++) {
        int row = row0A + wm + mi * 16 + quad * 4 + r;
        int b = row >> 11, s = row & 2047;
        unsigned short val = f2b(acc[mi][ni][r] + bv);
        if (slot == 0)      Qb[((long)(b * 16 + h) * 2048 + s) * 128 + d] = val;
        else if (slot == 1) Kb[((long)(b * 16 + h) * 2048 + s) * 128 + d] = val;
        else                Vt[((long)(b * 16 + h) * 128 + d) * 2048 + s] = val;
      }
    }
  }
}

// ---------------------------------------------------------------------------
__global__ __launch_bounds__(256)
void rope_inplace(unsigned short* __restrict__ Qb, unsigned short* __restrict__ Kb) {
  int wid  = blockIdx.x * 4 + (threadIdx.x >> 6);
  int j    = threadIdx.x & 63;
  int part = wid & 1;
  int s    = (wid >> 1) & 2047;
  int bh   = wid >> 12;
  unsigned short* buf = part ? Kb : Qb;
  long base = ((long)bh * 2048 + s) * 128;
  unsigned int pr = *(const unsigned int*)&buf[base + 2 * j];
  float x1 = b2f((unsigned short)(pr & 0xFFFFu));
  float x2 = b2f((unsigned short)(pr >> 16));
  float inv = powf(10000.0f, -(float)(2 * j) / 128.0f);
  float ang = (float)s * inv;
  float sn, cs;
  sincosf(ang, &sn, &cs);
  buf[base + j]      = f2b(x1 * cs - x2 * sn);
  buf[base + 64 + j] = f2b(x1 * sn + x2 * cs);
}

// ---------------------------------------------------------------------------
// Causal flash attention. Q,K (B,H,S,D); V^T (B,H,D,S). ctx -> (B,S,E) bf16.
// kv tile 64. Ks async-staged with 16-chunk XOR swizzle; Vs/Ps padded (72).
// ---------------------------------------------------------------------------
__global__ __launch_bounds__(256)
void attn_fwd(const unsigned short* __restrict__ Q,
              const unsigned short* __restrict__ K,
              const unsigned short* __restrict__ Vt,
              unsigned short* __restrict__ ctx) {
  __shared__ __align__(16) unsigned short Ks[64 * 128];   // swizzled
  __shared__ __align__(16) unsigned short Vs[128 * 72];   // [d][kv], padded
  __shared__ __align__(16) unsigned short Ps[4][32 * 72]; // per-wave P, padded
  const int bh = blockIdx.x;
  const int qt = blockIdx.y;
  const int tid = threadIdx.x;
  const int wave = tid >> 6, lane = tid & 63;
  const int quad = lane >> 4, l16 = lane & 15;
  const long base = (long)bh * 2048 * 128;
  const int q0 = qt * 128 + wave * 32;
  const float scale = 0.08838834764831845f;

  frag_ab qf[2][4];
#pragma unroll
  for (int mi = 0; mi < 2; mi++)
#pragma unroll
    for (int ks = 0; ks < 4; ks++)
      qf[mi][ks] = *(const frag_ab*)&Q[base + (long)(q0 + mi * 16 + l16) * 128 + ks * 32 + quad * 8];

  frag_cd o[2][8];
#pragma unroll
  for (int mi = 0; mi < 2; mi++)
#pragma unroll
    for (int ni = 0; ni < 8; ni++) o[mi][ni] = (frag_cd){0.f, 0.f, 0.f, 0.f};
  float m_i[2][4], l_i[2][4];
#pragma unroll
  for (int mi = 0; mi < 2; mi++)
#pragma unroll
    for (int r = 0; r < 4; r++) { m_i[mi][r] = -1.0e30f; l_i[mi][r] = 0.f; }

  const int kv_end = qt * 128 + 128;
  for (int kv0 = 0; kv0 < kv_end; kv0 += 64) {
    __syncthreads();
    // K: 16 KB -> 16 async 1KB stages (4/wave); row-chunk XOR-16 swizzle
#pragma unroll
    for (int i = 0; i < 4; i++) {
      int rbase = (wave * 4 + i) * 4;          // 4 rows per stage
      int r = rbase + (lane >> 4);
      int srcc = (lane & 15) ^ (r & 15);
      gload16(&K[base + (long)(kv0 + r) * 128 + srcc * 8], &Ks[rbase * 128]);
    }
    // V^T: 128 x 64, padded rows (4 uint4/thread)
#pragma unroll
    for (int i = 0; i < 4; i++) {
      int c = tid + i * 256;
      int d = c >> 3, ch = c & 7;
      *(uint4*)&Vs[d * 72 + ch * 8] =
          *(const uint4*)&Vt[(long)bh * 262144 + (long)d * 2048 + kv0 + ch * 8];
    }
    __syncthreads();

    // S = Q @ K^T (32x64 per wave)
    float p[2][4][4];
#pragma unroll
    for (int nj = 0; nj < 4; nj++) {
      frag_ab kf[4];
#pragma unroll
      for (int ks = 0; ks < 4; ks++) {
        int row = nj * 16 + l16;
        kf[ks] = *(const frag_ab*)&Ks[row * 128 + (((ks * 4 + quad) ^ (row & 15)) * 8)];
      }
#pragma unroll
      for (int mi = 0; mi < 2; mi++) {
        frag_cd acc = (frag_cd){0.f, 0.f, 0.f, 0.f};
#pragma unroll
        for (int ks = 0; ks < 4; ks++)
          acc = __builtin_amdgcn_mfma_f32_16x16x32_bf16(qf[mi][ks], kf[ks], acc, 0, 0, 0);
        int colg = kv0 + nj * 16 + l16;
#pragma unroll
        for (int r = 0; r < 4; r++) {
          int rowg = q0 + mi * 16 + quad * 4 + r;
          float sc = acc[r] * scale;
          p[mi][nj][r] = (colg <= rowg) ? sc : -10000.0f;
        }
      }
    }

    // online softmax
#pragma unroll
    for (int mi = 0; mi < 2; mi++) {
#pragma unroll
      for (int r = 0; r < 4; r++) {
        float mx = fmaxf(fmaxf(p[mi][0][r], p[mi][1][r]), fmaxf(p[mi][2][r], p[mi][3][r]));
#pragma unroll
        for (int off = 1; off < 16; off <<= 1)
          mx = fmaxf(mx, __shfl_xor(mx, off, 64));
        float mnew  = fmaxf(m_i[mi][r], mx);
        float alpha = __expf(m_i[mi][r] - mnew);
        float rs = 0.f;
#pragma unroll
        for (int nj = 0; nj < 4; nj++) {
          float e = __expf(p[mi][nj][r] - mnew);
          p[mi][nj][r] = e;
          rs += e;
        }
#pragma unroll
        for (int off = 1; off < 16; off <<= 1)
          rs += __shfl_xor(rs, off, 64);
        l_i[mi][r] = l_i[mi][r] * alpha + rs;
        m_i[mi][r] = mnew;
#pragma unroll
        for (int ni = 0; ni < 8; ni++) o[mi][ni][r] *= alpha;
      }
    }

    // P (C-layout) -> LDS (A-layout source)
    unsigned short* pw = &Ps[wave][0];
#pragma unroll
    for (int mi = 0; mi < 2; mi++)
#pragma unroll
      for (int nj = 0; nj < 4; nj++)
#pragma unroll
        for (int r = 0; r < 4; r++)
          pw[(mi * 16 + quad * 4 + r) * 72 + nj * 16 + l16] = f2b(p[mi][nj][r]);
    __syncthreads();

    // O += P @ V  (two K=32 steps over the 64-kv tile)
#pragma unroll
    for (int ni = 0; ni < 8; ni++) {
      frag_ab vf0 = *(const frag_ab*)&Vs[(ni * 16 + l16) * 72 + quad * 8];
      frag_ab vf1 = *(const frag_ab*)&Vs[(ni * 16 + l16) * 72 + 32 + quad * 8];
#pragma unroll
      for (int mi = 0; mi < 2; mi++) {
        frag_ab pf0 = *(const frag_ab*)&pw[(mi * 16 + l16) * 72 + quad * 8];
        frag_ab pf1 = *(const frag_ab*)&pw[(mi * 16 + l16) * 72 + 32 + quad * 8];
        o[mi][ni] = __builtin_amdgcn_mfma_f32_16x16x32_bf16(pf0, vf0, o[mi][ni], 0, 0, 0);
        o[mi][ni] = __builtin_amdgcn_mfma_f32_16x16x32_bf16(pf1, vf1, o[mi][ni], 0, 0, 0);
      }
    }
  }

  // ctx row-major (B,S,E)
  const int b = bh >> 4, h = bh & 15;
#pragma unroll
  for (int mi = 0; mi < 2; mi++) {
#pragma unroll
    for (int r = 0; r < 4; r++) {
      float inv = 1.0f / fmaxf(l_i[mi][r], 1.0e-20f);
      int s = q0 + mi * 16 + quad * 4 + r;
      long rowb = ((long)b * 2048 + s) * 2048 + h * 128;
#pragma unroll
      for (int ni = 0; ni < 8; ni++)
        ctx[rowb + ni * 16 + l16] = f2b(o[mi][ni][r] * inv);
    }
  }
}

// ---------------------------------------------------------------------------
// GEMM2: out(f32) = ctx(bf16 row-major) @ wo^T + wo_b
// ---------------------------------------------------------------------------
__global__ __launch_bounds__(256)
void gemm_ctx(const unsigned short* __restrict__ A,
              const float* __restrict__ Bw,
              const unsigned short* __restrict__ Bbf,
              const float* __restrict__ bias,
              float* __restrict__ C) {
  __shared__ __align__(16) unsigned short As[128 * 64];
  __shared__ __align__(16) unsigned short Bs[128 * 64];
  const int tid  = threadIdx.x;
  const int wave = tid >> 6, lane = tid & 63;
  const int quad = lane >> 4, l16 = lane & 15;
  const int wm = (wave & 1) * 64, wn = (wave >> 1) * 64;
  const int row0A = blockIdx.x * 128;
  const int row0B = blockIdx.y * 128;

  frag_cd acc[4][4];
#pragma unroll
  for (int i = 0; i < 4; i++)
#pragma unroll
    for (int j = 0; j < 4; j++) acc[i][j] = (frag_cd){0.f, 0.f, 0.f, 0.f};

  for (int k0 = 0; k0 < 2048; k0 += 64) {
    stage_a_async(A, As, row0A, k0, wave, lane, 2048);
    if (Bbf) stage_a_async(Bbf, Bs, row0B, k0, wave, lane, 2048);
    else     stage_b_cvt(Bw, Bs, row0B, k0, tid);
    __syncthreads();
#pragma unroll
    for (int kk = 0; kk < 64; kk += 32) {
      frag_ab af[4], bf[4];
#pragma unroll
      for (int mi = 0; mi < 4; mi++) {
        int row = wm + mi * 16 + l16;
        af[mi] = *(const frag_ab*)&As[row * 64 + (((quad + (kk >> 3)) ^ (l16 & 7)) * 8)];
      }
#pragma unroll
      for (int ni = 0; ni < 4; ni++) {
        int row = wn + ni * 16 + l16;
        bf[ni] = *(const frag_ab*)&Bs[row * 64 + (((quad + (kk >> 3)) ^ (l16 & 7)) * 8)];
      }
#pragma unroll
      for (int mi = 0; mi < 4; mi++)
#pragma unroll
        for (int ni = 0; ni < 4; ni++)
          acc[mi][ni] = __builtin_amdgcn_mfma_f32_16x16x32_bf16(af[mi], bf[ni], acc[mi][ni], 0, 0, 0);
    }
    __syncthreads();
  }
#pragma unroll
  for (int ni = 0; ni < 4; ni++) {
    int col = row0B + wn + ni * 16 + l16;
    float bv = bias[col];
#pragma unroll
    for (int mi = 0; mi < 4; mi++) {
#pragma unroll
      for (int r = 0; r < 4; r++) {
        int row = row0A + wm + mi * 16 + quad * 4 + r;
        C[(long)row * 2048 + col] = acc[mi][ni][r] + bv;
      }
    }
  }
}

// ---------------------------------------------------------------------------
extern "C" void kernel_launch(void* const* d_in, const int* in_sizes, int n_in,
                              void* d_out, int out_size, void* d_ws, size_t ws_size,
                              hipStream_t stream) {
  const float* x      = (const float*)d_in[0];
  const float* wqkv_w = (const float*)d_in[1];
  const float* wqkv_b = (const float*)d_in[2];
  const float* wo_w   = (const float*)d_in[3];
  const float* wo_b   = (const float*)d_in[4];

  unsigned short* xb  = (unsigned short*)d_out;              // [0,32MiB)
  unsigned short* Qb  = (unsigned short*)d_out + 16777216;   // [32,64MiB)
  unsigned short* Kb  = (unsigned short*)d_ws;               // ws [0,32MiB)
  unsigned short* Vt  = (unsigned short*)d_ws + 16777216;    // ws [32,64MiB)
  unsigned short* ctx = (unsigned short*)d_out;              // over xb (dead)
  float* outf = (float*)d_ws;                                // ws [0,64MiB)

  const bool big = ws_size >= 100663296UL;  // 96 MiB: room for bf16 weights
  unsigned short* Wq = big ? (unsigned short*)d_ws + 33554432 : nullptr; // [64,88MiB)
  unsigned short* Wo = big ? (unsigned short*)d_ws + 46137344 : nullptr; // [88,96MiB)

  // 0) conversions
  cvt_f32_bf16<<<8192, 256, 0, stream>>>(x, xb);
  if (big) {
    cvt_f32_bf16<<<6144, 256, 0, stream>>>(wqkv_w, Wq);
    cvt_f32_bf16<<<2048, 256, 0, stream>>>(wo_w, Wo);
  }
  // 1) QKV projection -> Q,K (bhsd), V^T (bhds)
  gemm_qkv<<<dim3(64, 48), 256, 0, stream>>>(xb, wqkv_w, Wq, wqkv_b, Qb, Kb, Vt);
  // 2) rope in place
  rope_inplace<<<65536, 256, 0, stream>>>(Qb, Kb);
  // 3) flash attention -> ctx (B,S,E) bf16
  attn_fwd<<<dim3(64, 16), 256, 0, stream>>>(Qb, Kb, Vt, ctx);
  // 4) output projection -> f32 ws, copy back
  gemm_ctx<<<dim3(64, 16), 256, 0, stream>>>(ctx, wo_w, Wo, wo_b, outf);
  hipMemcpyAsync(d_out, outf, 67108864UL, hipMemcpyDeviceToDevice, stream);
}